// Round 8
// baseline (335.562 us; speedup 1.0000x reference)
//
#include <hip/hip_runtime.h>

typedef unsigned short u16;
typedef short sh8 __attribute__((ext_vector_type(8)));     // bf16x8 MFMA frag
typedef float floatx4 __attribute__((ext_vector_type(4)));
typedef float float4v __attribute__((ext_vector_type(4)));
typedef u16 us8 __attribute__((ext_vector_type(8)));
typedef u16 us4 __attribute__((ext_vector_type(4)));

#define NB    16
#define NPTS  4096
#define MPTS  1024
#define CC1   256
#define CC2   512
#define KK1   768          // cc2 + cc1
#define CCO   256
#define MT    (NB*NPTS)    // 65536
#define MZ    (NB*MPTS)    // 16384

__device__ __forceinline__ float b2f(u16 u) {
    union { unsigned i; float f; } v; v.i = ((unsigned)u) << 16; return v.f;
}
__device__ __forceinline__ u16 f2b(float f) {
    union { float f; unsigned i; } v; v.f = f;
    unsigned u = v.i;
    unsigned r = (u + 0x7fffu + ((u >> 16) & 1u)) >> 16;
    return (u16)r;
}
// dtype-adaptive load/store: f32!=0 -> buffer is float, else bf16(u16)
__device__ __forceinline__ float ldv(const void* p, size_t i, int f32) {
    return f32 ? ((const float*)p)[i] : b2f(((const u16*)p)[i]);
}
__device__ __forceinline__ void stv(void* p, size_t i, int f32, float v) {
    if (f32) ((float*)p)[i] = v; else ((u16*)p)[i] = f2b(v);
}
__device__ __forceinline__ void gl_lds16(const void* g, void* l) {
    __builtin_amdgcn_global_load_lds(
        (const __attribute__((address_space(1))) void*)g,
        (__attribute__((address_space(3))) void*)l, 16, 0, 0);
}

// ---- prep (template symbol kept): flag + zero stats + weight converts -----
// Wa = W1[:, :512], Wbp = W1[:, 512:], W2b = W2.  1024 blocks x 256.
__global__ __launch_bounds__(256) void Pointnet_fp_module_33071248179394_kernel(
        const unsigned* g1bits, int* flag, float* stats,
        const void* W1, const void* W2, u16* Wa, u16* Wbp, u16* W2b) {
    const int f32 = (g1bits[0] == 0x3F800000u) ? 1 : 0;
    const int i = blockIdx.x * 256 + threadIdx.x;
    if (blockIdx.x == 0) {
        for (int k = threadIdx.x; k < 1024; k += 256) stats[k] = 0.f;
        if (threadIdx.x == 0) flag[0] = f32;
    }
    if (i < CCO * CC2) {
        int r = i >> 9, c = i & 511;
        Wa[i] = f2b(ldv(W1, (size_t)r * KK1 + c, f32));
    } else if (i < CCO * CC2 + CCO * CC1) {
        int k = i - CCO * CC2;
        int r = k >> 8, c = k & 255;
        Wbp[k] = f2b(ldv(W1, (size_t)r * KK1 + CC2 + c, f32));
    } else {
        int k = i - CCO * CC2 - CCO * CC1;
        W2b[k] = f2b(ldv(W2, k, f32));
    }
}

// ---------------- three_nn: fp32 distances + weights -----------------------
// 1024 blocks; block = 512 thr = 64 queries x 8-way point-split (128/thread).
__global__ __launch_bounds__(512) void three_nn_k(
        const int* flagp, const void* xyz1, const void* xyz2,
        int* nidx, float* nw) {
    __shared__ float4 P[MPTS];            // 16 KB
    __shared__ float md[512][3];
    __shared__ int   mi[512][3];
    const int f32 = flagp[0];
    const int bi = blockIdx.x >> 6;
    const int chunk = blockIdx.x & 63;
    const int t = threadIdx.x;
    const int ql = t & 63, sp = t >> 6;   // sp in [0,8)

    for (int p = t; p < MPTS; p += 512) {
        size_t s = (size_t)(bi * MPTS + p) * 3;
        P[p] = make_float4(ldv(xyz2, s, f32), ldv(xyz2, s + 1, f32),
                           ldv(xyz2, s + 2, f32), 0.f);
    }
    __syncthreads();

    const int q = chunk * 64 + ql;
    size_t s1 = (size_t)(bi * NPTS + q) * 3;
    const float qx = ldv(xyz1, s1 + 0, f32);
    const float qy = ldv(xyz1, s1 + 1, f32);
    const float qz = ldv(xyz1, s1 + 2, f32);

    float d0 = 3e38f, d1 = 3e38f, dv2 = 3e38f;
    int i0 = -1, i1 = -1, i2 = -1;
    const int jbeg = sp * 128, jend = jbeg + 128;
    #pragma unroll 4
    for (int j = jbeg; j < jend; j++) {
        float4 p = P[j];
        float dx = qx - p.x;
        float dy = qy - p.y;
        float dz = qz - p.z;
        float dd = fmaf(dx, dx, fmaf(dy, dy, dz * dz));
        if (dd < dv2) {
            if (dd < d0)      { dv2 = d1; i2 = i1; d1 = d0; i1 = i0; d0 = dd; i0 = j; }
            else if (dd < d1) { dv2 = d1; i2 = i1; d1 = dd; i1 = j; }
            else              { dv2 = dd; i2 = j; }
        }
    }
    md[t][0] = d0;  md[t][1] = d1;  md[t][2] = dv2;
    mi[t][0] = i0;  mi[t][1] = i1;  mi[t][2] = i2;
    __syncthreads();

    if (t < 64) {                          // merge 8 partials for query t
        float b0 = 3e38f, b1 = 3e38f, b2v = 3e38f;
        int j0 = -1, j1 = -1, j2 = -1;
        #pragma unroll
        for (int s = 0; s < 8; s++) {
            int base = s * 64 + t;
            #pragma unroll
            for (int k = 0; k < 3; k++) {
                float d = md[base][k];
                int ji = mi[base][k];
                if (d < b0)      { b2v = b1; j2 = j1; b1 = b0; j1 = j0; b0 = d; j0 = ji; }
                else if (d < b1) { b2v = b1; j2 = j1; b1 = d; j1 = ji; }
                else if (d < b2v){ b2v = d; j2 = ji; }
            }
        }
        float e0 = fminf(fmaxf(b0, 0.f), 1e-10f);
        float e1 = fminf(fmaxf(b1, 0.f), 1e-10f);
        float e2 = fminf(fmaxf(b2v, 0.f), 1e-10f);
        float v0 = 1.0f / e0, v1 = 1.0f / e1, v2 = 1.0f / e2;
        float s = v0 + v1 + v2;
        const size_t gq = ((size_t)bi * NPTS + chunk * 64 + t) * 3;
        nidx[gq + 0] = j0; nidx[gq + 1] = j1; nidx[gq + 2] = j2;
        nw[gq + 0] = v0 / s; nw[gq + 1] = v1 / s; nw[gq + 2] = v2 / s;
    }
}

// ------- Z-producer GEMM: Z(MZ,CCO) = points2(MZ,512) * Wa(CCO,512)^T ------
// A consumed DIRECTLY from points2 (bf16: gl_lds16; fp32: reg-staged f2b --
// identical bf16 values to the old pre-converted p2b path).
template<int K, int NW>
__global__ __launch_bounds__(128 * NW, 2) void gemm_z_k(
        const int* flagp, const void* __restrict__ A, const u16* __restrict__ B,
        u16* __restrict__ Y) {
    constexpr int T  = 128 * NW;
    constexpr int NT = NW * 64;
    __shared__ u16 As[128 * 32];
    __shared__ u16 Bs[NT * 32];
    const int f32 = flagp[0];
    const int tid = threadIdx.x;
    const int m0 = blockIdx.x * 128;
    const int n0 = blockIdx.y * NT;
    const int wave = tid >> 6, lane = tid & 63;
    const int wm = wave & 1, wn = wave >> 1;
    const int l16 = lane & 15, quad = lane >> 4;

    floatx4 acc[4][4];
    #pragma unroll
    for (int i = 0; i < 4; i++)
        #pragma unroll
        for (int j = 0; j < 4; j++)
            acc[i][j] = (floatx4){0.f, 0.f, 0.f, 0.f};

    for (int kb = 0; kb < K; kb += 32) {
        __syncthreads();
        #pragma unroll
        for (int c = tid; c < 512; c += T) {
            int row = c >> 2, c4 = c & 3;
            if (f32) {
                const float* ap = (const float*)A + (size_t)(m0 + row) * K + kb + c4 * 8;
                float4v a = *(const float4v*)ap;
                float4v b = *(const float4v*)(ap + 4);
                us8 o;
                #pragma unroll
                for (int k = 0; k < 4; k++) { o[k] = f2b(a[k]); o[k + 4] = f2b(b[k]); }
                *(us8*)(As + c * 8) = o;
            } else {
                gl_lds16((const u16*)A + (size_t)(m0 + row) * K + kb + c4 * 8,
                         As + c * 8);
            }
        }
        #pragma unroll
        for (int c = tid; c < NT * 4; c += T) {
            int row = c >> 2, c4 = c & 3;
            gl_lds16(B + (size_t)(n0 + row) * K + kb + c4 * 8, Bs + c * 8);
        }
        __syncthreads();

        sh8 af[4], bfr[4];
        #pragma unroll
        for (int i = 0; i < 4; i++)
            af[i] = *(const sh8*)(As + (wm * 64 + i * 16 + l16) * 32 + quad * 8);
        #pragma unroll
        for (int j = 0; j < 4; j++)
            bfr[j] = *(const sh8*)(Bs + (wn * 64 + j * 16 + l16) * 32 + quad * 8);
        #pragma unroll
        for (int i = 0; i < 4; i++)
            #pragma unroll
            for (int j = 0; j < 4; j++)
                acc[i][j] = __builtin_amdgcn_mfma_f32_16x16x32_bf16(
                                bfr[j], af[i], acc[i][j], 0, 0, 0);
    }

    #pragma unroll
    for (int i = 0; i < 4; i++) {
        int row = m0 + wm * 64 + i * 16 + l16;
        #pragma unroll
        for (int j = 0; j < 4; j++) {
            int colb = wn * 64 + j * 16 + quad * 4;
            us4 o;
            #pragma unroll
            for (int r = 0; r < 4; r++)
                o[r] = f2b(acc[i][j][r]);
            *(us4*)(Y + (size_t)row * CCO + n0 + colb) = o;
        }
    }
}

// ------- M-tall GEMM: 64-row x 256-col tile, 256 thr, 1024 blocks ----------
// 4 blocks/CU (LDS ~36KB) -> 4 independent stage streams per CU (vs 2 at
// 128-row tiles; R3's 1024-block grid beat both 512-block variants).
// A-tile (64x256 bf16 = 32KB) staged ONCE into XOR-swizzled LDS; barrier-free
// K-loop (ds_read A + B direct from L2-hot global + MFMA).
// GATHER: A = points1 DIRECT (bf16: gl_lds16 pre-swizzled src; fp32: reg f2b)
//         + SUM_k w_k * Z[gather] epilogue + stats1.
// BN1:    A = raw y1; BN+ReLU applied during reg-staging; + stats2.
template<bool GATHER, bool BN1>
__global__ __launch_bounds__(256, 4) void gemm_mt_k(
        const int* flagp, const void* __restrict__ Asrc,
        const u16* __restrict__ B, const void* __restrict__ bias,
        const int* __restrict__ nidx, const float* __restrict__ nw,
        const u16* __restrict__ Zb,
        u16* __restrict__ Y, float* __restrict__ sum, float* __restrict__ sq,
        const float* __restrict__ nsum, const float* __restrict__ nsq,
        const void* __restrict__ ng, const void* __restrict__ nbeta) {
    __shared__ u16 As[64 * 256];                  // 32 KB, swizzled
    __shared__ float sSum[256], sSq[256];
    __shared__ int   sIdx[GATHER ? 192 : 1];
    __shared__ float sW[GATHER ? 192 : 1];
    __shared__ float ssc[BN1 ? 256 : 1], ssh[BN1 ? 256 : 1];
    const int f32 = flagp[0];
    const int tid = threadIdx.x;
    const int m0 = blockIdx.x * 64;
    const int wn = tid >> 6, lane = tid & 63;     // 4 waves = 4 N-columns
    const int l16 = lane & 15, quad = lane >> 4;

    sSum[tid] = 0.f; sSq[tid] = 0.f;
    if (BN1) {
        const float invM = 1.0f / (float)MT;
        float mean = nsum[tid] * invM;
        float var = nsq[tid] * invM - mean * mean;
        float sc = rsqrtf(var + 1e-5f) * ldv(ng, tid, f32);
        ssc[tid] = sc;
        ssh[tid] = ldv(nbeta, tid, f32) - mean * sc;
    }
    if (GATHER && tid < 64) {             // stage gather idx/w for 64 rows
        size_t q3 = (size_t)(m0 + tid) * 3;
        #pragma unroll
        for (int k = 0; k < 3; k++) {
            sIdx[tid * 3 + k] = nidx[q3 + k];
            sW[tid * 3 + k]   = nw[q3 + k];
        }
    }
    if (BN1) __syncthreads();             // ssc/ssh ready before staging

    // ---- stage whole A tile, swizzled: LDS chunk (r,cp) <- global chunk
    // ---- cp^(r&7).  2048 chunks of 16B, 8 per thread.
    #pragma unroll
    for (int c = tid; c < 2048; c += 256) {
        int r = c >> 5, cp = c & 31;
        int col = ((cp ^ (r & 7)) << 3);
        if (BN1) {
            us8 a = *(const us8*)((const u16*)Asrc + (size_t)(m0 + r) * 256 + col);
            us8 o;
            #pragma unroll
            for (int k = 0; k < 8; k++)
                o[k] = f2b(fmaxf(b2f((u16)a[k]) * ssc[col + k] + ssh[col + k], 0.f));
            *(us8*)(As + c * 8) = o;
        } else if (f32) {
            const float* ap = (const float*)Asrc + (size_t)(m0 + r) * 256 + col;
            float4v a = *(const float4v*)ap;
            float4v b = *(const float4v*)(ap + 4);
            us8 o;
            #pragma unroll
            for (int k = 0; k < 4; k++) { o[k] = f2b(a[k]); o[k + 4] = f2b(b[k]); }
            *(us8*)(As + c * 8) = o;
        } else {
            gl_lds16((const u16*)Asrc + (size_t)(m0 + r) * 256 + col, As + c * 8);
        }
    }
    __syncthreads();                      // the only barrier

    floatx4 acc[4][4];
    #pragma unroll
    for (int i = 0; i < 4; i++)
        #pragma unroll
        for (int j = 0; j < 4; j++)
            acc[i][j] = (floatx4){0.f, 0.f, 0.f, 0.f};

    #pragma unroll 2
    for (int kb = 0; kb < 256; kb += 32) {
        sh8 af[4], bfr[4];
        #pragma unroll
        for (int j = 0; j < 4; j++)
            bfr[j] = *(const sh8*)(B + (size_t)(wn * 64 + j * 16 + l16) * 256
                                     + kb + quad * 8);
        #pragma unroll
        for (int i = 0; i < 4; i++) {
            int r = i * 16 + l16;
            int cp = ((kb >> 3) + quad) ^ (l16 & 7);
            af[i] = *(const sh8*)(As + r * 256 + (cp << 3));
        }
        #pragma unroll
        for (int i = 0; i < 4; i++)
            #pragma unroll
            for (int j = 0; j < 4; j++)
                acc[i][j] = __builtin_amdgcn_mfma_f32_16x16x32_bf16(
                                bfr[j], af[i], acc[i][j], 0, 0, 0);
    }

    float bvv[4][4];
    #pragma unroll
    for (int j = 0; j < 4; j++)
        #pragma unroll
        for (int r = 0; r < 4; r++)
            bvv[j][r] = ldv(bias, wn * 64 + j * 16 + quad * 4 + r, f32);

    float cs[4][4], css[4][4];
    #pragma unroll
    for (int j = 0; j < 4; j++)
        #pragma unroll
        for (int r = 0; r < 4; r++) { cs[j][r] = 0.f; css[j][r] = 0.f; }

    const int zbase = GATHER ? ((m0 >> 12) << 10) : 0;
    #pragma unroll
    for (int i = 0; i < 4; i++) {
        int rl = i * 16 + l16;
        const u16 *z0 = nullptr, *z1 = nullptr, *z2 = nullptr;
        float w0 = 0.f, w1 = 0.f, w2 = 0.f;
        if (GATHER) {
            int i0 = sIdx[rl * 3 + 0], i1 = sIdx[rl * 3 + 1], i2 = sIdx[rl * 3 + 2];
            w0 = sW[rl * 3 + 0]; w1 = sW[rl * 3 + 1]; w2 = sW[rl * 3 + 2];
            z0 = Zb + (size_t)(zbase + i0) * CCO;
            z1 = Zb + (size_t)(zbase + i1) * CCO;
            z2 = Zb + (size_t)(zbase + i2) * CCO;
        }
        u16* yrow = Y + (size_t)(m0 + rl) * CCO;
        #pragma unroll
        for (int j = 0; j < 4; j++) {
            int colb = wn * 64 + j * 16 + quad * 4;
            us4 o;
            if (GATHER) {
                us4 zv0 = *(const us4*)(z0 + colb);
                us4 zv1 = *(const us4*)(z1 + colb);
                us4 zv2 = *(const us4*)(z2 + colb);
                #pragma unroll
                for (int r = 0; r < 4; r++) {
                    float v = acc[i][j][r] + bvv[j][r]
                            + w0 * b2f((u16)zv0[r]) + w1 * b2f((u16)zv1[r])
                            + w2 * b2f((u16)zv2[r]);
                    cs[j][r] += v; css[j][r] += v * v;
                    o[r] = f2b(v);
                }
            } else {
                #pragma unroll
                for (int r = 0; r < 4; r++) {
                    float v = acc[i][j][r] + bvv[j][r];
                    cs[j][r] += v; css[j][r] += v * v;
                    o[r] = f2b(v);
                }
            }
            *(us4*)(yrow + colb) = o;
        }
    }
    #pragma unroll
    for (int j = 0; j < 4; j++)
        #pragma unroll
        for (int r = 0; r < 4; r++) {
            float a = cs[j][r], b = css[j][r];
            #pragma unroll
            for (int m = 1; m < 16; m <<= 1) {
                a += __shfl_xor(a, m, 64);
                b += __shfl_xor(b, m, 64);
            }
            if (l16 == 0) {
                int cl = wn * 64 + j * 16 + quad * 4 + r;
                atomicAdd(&sSum[cl], a);
                atomicAdd(&sSq[cl], b);
            }
        }
    __syncthreads();
    atomicAdd(&sum[tid], sSum[tid]);
    atomicAdd(&sq[tid], sSq[tid]);
}

// ------- BN apply + ReLU + transpose to (b, C, n); out dtype-adaptive ------
__global__ void bn_out_k(const int* flagp, const u16* Y, void* Out,
                         const float* sum, const float* sq,
                         const void* g, const void* beta) {
    __shared__ float tile[64][65];
    const int f32 = flagp[0];
    const int bi = blockIdx.z;
    const int p0 = blockIdx.x * 64;
    const int c0 = blockIdx.y * 64;
    const int t = threadIdx.x;
    const int cr = t & 63, rq = t >> 6;
    const float invM = 1.0f / (float)MT;

    const int c = c0 + cr;
    float mean = sum[c] * invM;
    float var = sq[c] * invM - mean * mean;
    float sc = rsqrtf(var + 1e-5f) * ldv(g, c, f32);
    float sh = ldv(beta, c, f32) - mean * sc;

    for (int r = rq; r < 64; r += 4) {
        int m = bi * NPTS + p0 + r;
        float v = b2f(Y[(size_t)m * CCO + c]) * sc + sh;
        tile[r][cr] = fmaxf(v, 0.f);
    }
    __syncthreads();
    for (int r = rq; r < 64; r += 4) {
        size_t o = ((size_t)bi * CCO + (c0 + r)) * NPTS + p0 + cr;
        stv(Out, o, f32, tile[cr][r]);
    }
}

extern "C" void kernel_launch(void* const* d_in, const int* in_sizes, int n_in,
                              void* d_out, int out_size, void* d_ws, size_t ws_size,
                              hipStream_t stream) {
    const void* xyz1    = d_in[0];
    const void* xyz2    = d_in[1];
    const void* points1 = d_in[2];
    const void* points2 = d_in[3];
    const void* W1      = d_in[4];
    const void* b1      = d_in[5];
    const void* g1      = d_in[6];
    const void* be1     = d_in[7];
    const void* W2      = d_in[8];
    const void* b2      = d_in[9];
    const void* g2      = d_in[10];
    const void* be2     = d_in[11];
    char* ws = (char*)d_ws;

    int*   flag  = (int*)(ws + 0);
    float* sum1  = (float*)(ws + 4096);
    float* sq1   = (float*)(ws + 5120);
    float* sum2  = (float*)(ws + 6144);
    float* sq2   = (float*)(ws + 7168);
    int*   nidx  = (int*)(ws + 20480);             // 786432 B
    float* nw    = (float*)(ws + 806912);          // 786432 B, ends 1593344
    u16* Wa   = (u16*)(ws + 2097152);              // 256 KB  (W1[:, :512])
    u16* Wbp  = (u16*)(ws + 2359296);              // 128 KB  (W1[:, 512:])
    u16* W2b  = (u16*)(ws + 2490368);              // 128 KB
    u16* Z    = (u16*)(ws + 2621440);              // 8.4 MB  (16384 x 256)
    u16* y1   = (u16*)(ws + 11010048ULL);          // 33.6 MB (raw, pre-BN)
    u16* y2   = (u16*)(ws + 44564480ULL);          // 33.6 MB, ends 78118912

    Pointnet_fp_module_33071248179394_kernel<<<dim3(1024), dim3(256), 0, stream>>>(
        (const unsigned*)g1, flag, (float*)(ws + 4096), W1, W2, Wa, Wbp, W2b);
    three_nn_k<<<dim3(1024), dim3(512), 0, stream>>>(flag, xyz1, xyz2, nidx, nw);
    gemm_z_k<CC2, 2><<<dim3(MZ / 128, 2), dim3(256), 0, stream>>>(
        flag, points2, Wa, Z);
    gemm_mt_k<true, false><<<dim3(MT / 64), dim3(256), 0, stream>>>(
        flag, points1, Wbp, b1, nidx, nw, Z, y1, sum1, sq1,
        nullptr, nullptr, nullptr, nullptr);
    gemm_mt_k<false, true><<<dim3(MT / 64), dim3(256), 0, stream>>>(
        flag, y1, W2b, b2, nullptr, nullptr, nullptr, y2, sum2, sq2,
        sum1, sq1, g1, be1);
    bn_out_k<<<dim3(64, 4, NB), dim3(256), 0, stream>>>(
        flag, y2, d_out, sum2, sq2, g2, be2);
}

// Round 9
// 311.322 us; speedup vs baseline: 1.0779x; 1.0779x over previous
//
#include <hip/hip_runtime.h>

typedef unsigned short u16;
typedef short sh8 __attribute__((ext_vector_type(8)));     // bf16x8 MFMA frag
typedef float floatx4 __attribute__((ext_vector_type(4)));
typedef float float4v __attribute__((ext_vector_type(4)));
typedef u16 us8 __attribute__((ext_vector_type(8)));
typedef u16 us4 __attribute__((ext_vector_type(4)));

#define NB    16
#define NPTS  4096
#define MPTS  1024
#define CC1   256
#define CC2   512
#define KK1   768          // cc2 + cc1
#define CCO   256
#define MT    (NB*NPTS)    // 65536
#define MZ    (NB*MPTS)    // 16384

__device__ __forceinline__ float b2f(u16 u) {
    union { unsigned i; float f; } v; v.i = ((unsigned)u) << 16; return v.f;
}
__device__ __forceinline__ u16 f2b(float f) {
    union { float f; unsigned i; } v; v.f = f;
    unsigned u = v.i;
    unsigned r = (u + 0x7fffu + ((u >> 16) & 1u)) >> 16;
    return (u16)r;
}
// dtype-adaptive load/store: f32!=0 -> buffer is float, else bf16(u16)
__device__ __forceinline__ float ldv(const void* p, size_t i, int f32) {
    return f32 ? ((const float*)p)[i] : b2f(((const u16*)p)[i]);
}
__device__ __forceinline__ void stv(void* p, size_t i, int f32, float v) {
    if (f32) ((float*)p)[i] = v; else ((u16*)p)[i] = f2b(v);
}
__device__ __forceinline__ void gl_lds16(const void* g, void* l) {
    __builtin_amdgcn_global_load_lds(
        (const __attribute__((address_space(1))) void*)g,
        (__attribute__((address_space(3))) void*)l, 16, 0, 0);
}

// ---- prep (template symbol kept): flag + zero stats + weight converts -----
__global__ __launch_bounds__(256) void Pointnet_fp_module_33071248179394_kernel(
        const unsigned* g1bits, int* flag, float* stats,
        const void* W1, const void* W2, u16* Wa, u16* Wbp, u16* W2b) {
    const int f32 = (g1bits[0] == 0x3F800000u) ? 1 : 0;
    const int i = blockIdx.x * 256 + threadIdx.x;
    if (blockIdx.x == 0) {
        for (int k = threadIdx.x; k < 1024; k += 256) stats[k] = 0.f;
        if (threadIdx.x == 0) flag[0] = f32;
    }
    if (i < CCO * CC2) {
        int r = i >> 9, c = i & 511;
        Wa[i] = f2b(ldv(W1, (size_t)r * KK1 + c, f32));
    } else if (i < CCO * CC2 + CCO * CC1) {
        int k = i - CCO * CC2;
        int r = k >> 8, c = k & 255;
        Wbp[k] = f2b(ldv(W1, (size_t)r * KK1 + CC2 + c, f32));
    } else {
        int k = i - CCO * CC2 - CCO * CC1;
        W2b[k] = f2b(ldv(W2, k, f32));
    }
}

// ---------------- three_nn: fp32 distances + weights -----------------------
__global__ __launch_bounds__(512) void three_nn_k(
        const int* flagp, const void* xyz1, const void* xyz2,
        int* nidx, float* nw) {
    __shared__ float4 P[MPTS];            // 16 KB
    __shared__ float md[512][3];
    __shared__ int   mi[512][3];
    const int f32 = flagp[0];
    const int bi = blockIdx.x >> 6;
    const int chunk = blockIdx.x & 63;
    const int t = threadIdx.x;
    const int ql = t & 63, sp = t >> 6;   // sp in [0,8)

    for (int p = t; p < MPTS; p += 512) {
        size_t s = (size_t)(bi * MPTS + p) * 3;
        P[p] = make_float4(ldv(xyz2, s, f32), ldv(xyz2, s + 1, f32),
                           ldv(xyz2, s + 2, f32), 0.f);
    }
    __syncthreads();

    const int q = chunk * 64 + ql;
    size_t s1 = (size_t)(bi * NPTS + q) * 3;
    const float qx = ldv(xyz1, s1 + 0, f32);
    const float qy = ldv(xyz1, s1 + 1, f32);
    const float qz = ldv(xyz1, s1 + 2, f32);

    float d0 = 3e38f, d1 = 3e38f, dv2 = 3e38f;
    int i0 = -1, i1 = -1, i2 = -1;
    const int jbeg = sp * 128, jend = jbeg + 128;
    #pragma unroll 4
    for (int j = jbeg; j < jend; j++) {
        float4 p = P[j];
        float dx = qx - p.x;
        float dy = qy - p.y;
        float dz = qz - p.z;
        float dd = fmaf(dx, dx, fmaf(dy, dy, dz * dz));
        if (dd < dv2) {
            if (dd < d0)      { dv2 = d1; i2 = i1; d1 = d0; i1 = i0; d0 = dd; i0 = j; }
            else if (dd < d1) { dv2 = d1; i2 = i1; d1 = dd; i1 = j; }
            else              { dv2 = dd; i2 = j; }
        }
    }
    md[t][0] = d0;  md[t][1] = d1;  md[t][2] = dv2;
    mi[t][0] = i0;  mi[t][1] = i1;  mi[t][2] = i2;
    __syncthreads();

    if (t < 64) {                          // merge 8 partials for query t
        float b0 = 3e38f, b1 = 3e38f, b2v = 3e38f;
        int j0 = -1, j1 = -1, j2 = -1;
        #pragma unroll
        for (int s = 0; s < 8; s++) {
            int base = s * 64 + t;
            #pragma unroll
            for (int k = 0; k < 3; k++) {
                float d = md[base][k];
                int ji = mi[base][k];
                if (d < b0)      { b2v = b1; j2 = j1; b1 = b0; j1 = j0; b0 = d; j0 = ji; }
                else if (d < b1) { b2v = b1; j2 = j1; b1 = d; j1 = ji; }
                else if (d < b2v){ b2v = d; j2 = ji; }
            }
        }
        float e0 = fminf(fmaxf(b0, 0.f), 1e-10f);
        float e1 = fminf(fmaxf(b1, 0.f), 1e-10f);
        float e2 = fminf(fmaxf(b2v, 0.f), 1e-10f);
        float v0 = 1.0f / e0, v1 = 1.0f / e1, v2 = 1.0f / e2;
        float s = v0 + v1 + v2;
        const size_t gq = ((size_t)bi * NPTS + chunk * 64 + t) * 3;
        nidx[gq + 0] = j0; nidx[gq + 1] = j1; nidx[gq + 2] = j2;
        nw[gq + 0] = v0 / s; nw[gq + 1] = v1 / s; nw[gq + 2] = v2 / s;
    }
}

// ------- Z-producer GEMM: Z(MZ,CCO) = points2(MZ,512) * Wa(CCO,512)^T ------
template<int K, int NW>
__global__ __launch_bounds__(128 * NW, 2) void gemm_z_k(
        const int* flagp, const void* __restrict__ A, const u16* __restrict__ B,
        u16* __restrict__ Y) {
    constexpr int T  = 128 * NW;
    constexpr int NT = NW * 64;
    __shared__ u16 As[128 * 32];
    __shared__ u16 Bs[NT * 32];
    const int f32 = flagp[0];
    const int tid = threadIdx.x;
    const int m0 = blockIdx.x * 128;
    const int n0 = blockIdx.y * NT;
    const int wave = tid >> 6, lane = tid & 63;
    const int wm = wave & 1, wn = wave >> 1;
    const int l16 = lane & 15, quad = lane >> 4;

    floatx4 acc[4][4];
    #pragma unroll
    for (int i = 0; i < 4; i++)
        #pragma unroll
        for (int j = 0; j < 4; j++)
            acc[i][j] = (floatx4){0.f, 0.f, 0.f, 0.f};

    for (int kb = 0; kb < K; kb += 32) {
        __syncthreads();
        #pragma unroll
        for (int c = tid; c < 512; c += T) {
            int row = c >> 2, c4 = c & 3;
            if (f32) {
                const float* ap = (const float*)A + (size_t)(m0 + row) * K + kb + c4 * 8;
                float4v a = *(const float4v*)ap;
                float4v b = *(const float4v*)(ap + 4);
                us8 o;
                #pragma unroll
                for (int k = 0; k < 4; k++) { o[k] = f2b(a[k]); o[k + 4] = f2b(b[k]); }
                *(us8*)(As + c * 8) = o;
            } else {
                gl_lds16((const u16*)A + (size_t)(m0 + row) * K + kb + c4 * 8,
                         As + c * 8);
            }
        }
        #pragma unroll
        for (int c = tid; c < NT * 4; c += T) {
            int row = c >> 2, c4 = c & 3;
            gl_lds16(B + (size_t)(n0 + row) * K + kb + c4 * 8, Bs + c * 8);
        }
        __syncthreads();

        sh8 af[4], bfr[4];
        #pragma unroll
        for (int i = 0; i < 4; i++)
            af[i] = *(const sh8*)(As + (wm * 64 + i * 16 + l16) * 32 + quad * 8);
        #pragma unroll
        for (int j = 0; j < 4; j++)
            bfr[j] = *(const sh8*)(Bs + (wn * 64 + j * 16 + l16) * 32 + quad * 8);
        #pragma unroll
        for (int i = 0; i < 4; i++)
            #pragma unroll
            for (int j = 0; j < 4; j++)
                acc[i][j] = __builtin_amdgcn_mfma_f32_16x16x32_bf16(
                                bfr[j], af[i], acc[i][j], 0, 0, 0);
    }

    #pragma unroll
    for (int i = 0; i < 4; i++) {
        int row = m0 + wm * 64 + i * 16 + l16;
        #pragma unroll
        for (int j = 0; j < 4; j++) {
            int colb = wn * 64 + j * 16 + quad * 4;
            us4 o;
            #pragma unroll
            for (int r = 0; r < 4; r++)
                o[r] = f2b(acc[i][j][r]);
            *(us4*)(Y + (size_t)row * CCO + n0 + colb) = o;
        }
    }
}

// ------- M-tall GEMM, R3-proven structure: 128x128 tile, 256 thr, ----------
// 2-barrier K-loop, 1024 blocks (1D, XCD-chunked swizzle: each XCD gets 2
// contiguous batches -> 1MB Z slice fits per-XCD L2; the two N-blocks of an
// A-panel land on the same XCD -> A re-read is L2-hit).
// GATHER: A = points1 direct (bf16: gl_lds16 identical bytes; fp32: reg f2b)
//         + SUM_k w_k * Z[gather] epilogue + stats1.
// BN1:    A = raw y1; BN+ReLU applied during reg-staging (stats from nsum/
//         nsq) + stats2.  Swapped-operand epilogue, shfl-reduced stats.
template<bool GATHER, bool BN1>
__global__ __launch_bounds__(256, 2) void gemm_mt_k(
        const int* flagp, const void* __restrict__ Asrc,
        const u16* __restrict__ B, const void* __restrict__ bias,
        const int* __restrict__ nidx, const float* __restrict__ nw,
        const u16* __restrict__ Zb,
        u16* __restrict__ Y, float* __restrict__ sum, float* __restrict__ sq,
        const float* __restrict__ nsum, const float* __restrict__ nsq,
        const void* __restrict__ ng, const void* __restrict__ nbeta) {
    __shared__ u16 As[128 * 32];
    __shared__ u16 Bs[128 * 32];
    __shared__ float sSum[128], sSq[128];
    __shared__ int   sIdx[GATHER ? 384 : 1];
    __shared__ float sW[GATHER ? 384 : 1];
    __shared__ float ssc[BN1 ? 256 : 1], ssh[BN1 ? 256 : 1];
    const int f32 = flagp[0];
    const int tid = threadIdx.x;
    // XCD-chunked bijective swizzle (1024 % 8 == 0)
    const int rb = (blockIdx.x & 7) * 128 + (blockIdx.x >> 3);
    const int m0 = (rb >> 1) * 128;
    const int n0 = (rb & 1) * 128;
    const int wave = tid >> 6, lane = tid & 63;
    const int wm = wave & 1, wn = wave >> 1;
    const int l16 = lane & 15, quad = lane >> 4;

    if (tid < 128) { sSum[tid] = 0.f; sSq[tid] = 0.f; }
    if (BN1 && tid < 256) {
        const float invM = 1.0f / (float)MT;
        float mean = nsum[tid] * invM;
        float var = nsq[tid] * invM - mean * mean;
        float sc = rsqrtf(var + 1e-5f) * ldv(ng, tid, f32);
        ssc[tid] = sc;
        ssh[tid] = ldv(nbeta, tid, f32) - mean * sc;
    }
    if (GATHER && tid < 128) {            // stage gather idx/w for 128 rows
        size_t q3 = (size_t)(m0 + tid) * 3;
        #pragma unroll
        for (int k = 0; k < 3; k++) {
            sIdx[tid * 3 + k] = nidx[q3 + k];
            sW[tid * 3 + k]   = nw[q3 + k];
        }
    }

    floatx4 acc[4][4];
    #pragma unroll
    for (int i = 0; i < 4; i++)
        #pragma unroll
        for (int j = 0; j < 4; j++)
            acc[i][j] = (floatx4){0.f, 0.f, 0.f, 0.f};

    constexpr int K = 256;
    for (int kb = 0; kb < K; kb += 32) {
        __syncthreads();
        #pragma unroll
        for (int c = tid; c < 512; c += 256) {     // A: 128 rows x 32 cols
            int row = c >> 2, c4 = c & 3;
            if (BN1) {
                us8 a = *(const us8*)((const u16*)Asrc
                            + (size_t)(m0 + row) * K + kb + c4 * 8);
                us8 o;
                #pragma unroll
                for (int k = 0; k < 8; k++) {
                    int ch = kb + c4 * 8 + k;
                    o[k] = f2b(fmaxf(b2f((u16)a[k]) * ssc[ch] + ssh[ch], 0.f));
                }
                *(us8*)(As + c * 8) = o;
            } else if (f32) {
                const float* ap = (const float*)Asrc
                            + (size_t)(m0 + row) * K + kb + c4 * 8;
                float4v a = *(const float4v*)ap;
                float4v b = *(const float4v*)(ap + 4);
                us8 o;
                #pragma unroll
                for (int k = 0; k < 4; k++) { o[k] = f2b(a[k]); o[k + 4] = f2b(b[k]); }
                *(us8*)(As + c * 8) = o;
            } else {
                gl_lds16((const u16*)Asrc + (size_t)(m0 + row) * K + kb + c4 * 8,
                         As + c * 8);
            }
        }
        #pragma unroll
        for (int c = tid; c < 512; c += 256) {     // B: 128 rows x 32 cols
            int row = c >> 2, c4 = c & 3;
            gl_lds16(B + (size_t)(n0 + row) * K + kb + c4 * 8, Bs + c * 8);
        }
        __syncthreads();

        sh8 af[4], bfr[4];
        #pragma unroll
        for (int i = 0; i < 4; i++)
            af[i] = *(const sh8*)(As + (wm * 64 + i * 16 + l16) * 32 + quad * 8);
        #pragma unroll
        for (int j = 0; j < 4; j++)
            bfr[j] = *(const sh8*)(Bs + (wn * 64 + j * 16 + l16) * 32 + quad * 8);
        #pragma unroll
        for (int i = 0; i < 4; i++)
            #pragma unroll
            for (int j = 0; j < 4; j++)
                acc[i][j] = __builtin_amdgcn_mfma_f32_16x16x32_bf16(
                                bfr[j], af[i], acc[i][j], 0, 0, 0);
    }

    float bvv[4][4];
    #pragma unroll
    for (int j = 0; j < 4; j++)
        #pragma unroll
        for (int r = 0; r < 4; r++)
            bvv[j][r] = ldv(bias, n0 + wn * 64 + j * 16 + quad * 4 + r, f32);

    float cs[4][4], css[4][4];
    #pragma unroll
    for (int j = 0; j < 4; j++)
        #pragma unroll
        for (int r = 0; r < 4; r++) { cs[j][r] = 0.f; css[j][r] = 0.f; }

    const int zbase = GATHER ? ((m0 >> 12) << 10) : 0;
    #pragma unroll
    for (int i = 0; i < 4; i++) {
        int rl = wm * 64 + i * 16 + l16;
        const u16 *z0 = nullptr, *z1 = nullptr, *z2 = nullptr;
        float w0 = 0.f, w1 = 0.f, w2 = 0.f;
        if (GATHER) {
            int i0 = sIdx[rl * 3 + 0], i1 = sIdx[rl * 3 + 1], i2 = sIdx[rl * 3 + 2];
            w0 = sW[rl * 3 + 0]; w1 = sW[rl * 3 + 1]; w2 = sW[rl * 3 + 2];
            z0 = Zb + (size_t)(zbase + i0) * CCO + n0;
            z1 = Zb + (size_t)(zbase + i1) * CCO + n0;
            z2 = Zb + (size_t)(zbase + i2) * CCO + n0;
        }
        u16* yrow = Y + (size_t)(m0 + rl) * CCO + n0;
        #pragma unroll
        for (int j = 0; j < 4; j++) {
            int colb = wn * 64 + j * 16 + quad * 4;
            us4 o;
            if (GATHER) {
                us4 zv0 = *(const us4*)(z0 + colb);
                us4 zv1 = *(const us4*)(z1 + colb);
                us4 zv2 = *(const us4*)(z2 + colb);
                #pragma unroll
                for (int r = 0; r < 4; r++) {
                    float v = acc[i][j][r] + bvv[j][r]
                            + w0 * b2f((u16)zv0[r]) + w1 * b2f((u16)zv1[r])
                            + w2 * b2f((u16)zv2[r]);
                    cs[j][r] += v; css[j][r] += v * v;
                    o[r] = f2b(v);
                }
            } else {
                #pragma unroll
                for (int r = 0; r < 4; r++) {
                    float v = acc[i][j][r] + bvv[j][r];
                    cs[j][r] += v; css[j][r] += v * v;
                    o[r] = f2b(v);
                }
            }
            *(us4*)(yrow + colb) = o;
        }
    }
    #pragma unroll
    for (int j = 0; j < 4; j++)
        #pragma unroll
        for (int r = 0; r < 4; r++) {
            float a = cs[j][r], b = css[j][r];
            #pragma unroll
            for (int m = 1; m < 16; m <<= 1) {
                a += __shfl_xor(a, m, 64);
                b += __shfl_xor(b, m, 64);
            }
            if (l16 == 0) {
                int cl = wn * 64 + j * 16 + quad * 4 + r;
                atomicAdd(&sSum[cl], a);
                atomicAdd(&sSq[cl], b);
            }
        }
    __syncthreads();
    if (tid < 128) {
        atomicAdd(&sum[n0 + tid], sSum[tid]);
        atomicAdd(&sq[n0 + tid], sSq[tid]);
    }
}

// ------- BN apply + ReLU + transpose to (b, C, n); out dtype-adaptive ------
__global__ void bn_out_k(const int* flagp, const u16* Y, void* Out,
                         const float* sum, const float* sq,
                         const void* g, const void* beta) {
    __shared__ float tile[64][65];
    const int f32 = flagp[0];
    const int bi = blockIdx.z;
    const int p0 = blockIdx.x * 64;
    const int c0 = blockIdx.y * 64;
    const int t = threadIdx.x;
    const int cr = t & 63, rq = t >> 6;
    const float invM = 1.0f / (float)MT;

    const int c = c0 + cr;
    float mean = sum[c] * invM;
    float var = sq[c] * invM - mean * mean;
    float sc = rsqrtf(var + 1e-5f) * ldv(g, c, f32);
    float sh = ldv(beta, c, f32) - mean * sc;

    for (int r = rq; r < 64; r += 4) {
        int m = bi * NPTS + p0 + r;
        float v = b2f(Y[(size_t)m * CCO + c]) * sc + sh;
        tile[r][cr] = fmaxf(v, 0.f);
    }
    __syncthreads();
    for (int r = rq; r < 64; r += 4) {
        size_t o = ((size_t)bi * CCO + (c0 + r)) * NPTS + p0 + cr;
        stv(Out, o, f32, tile[cr][r]);
    }
}

extern "C" void kernel_launch(void* const* d_in, const int* in_sizes, int n_in,
                              void* d_out, int out_size, void* d_ws, size_t ws_size,
                              hipStream_t stream) {
    const void* xyz1    = d_in[0];
    const void* xyz2    = d_in[1];
    const void* points1 = d_in[2];
    const void* points2 = d_in[3];
    const void* W1      = d_in[4];
    const void* b1      = d_in[5];
    const void* g1      = d_in[6];
    const void* be1     = d_in[7];
    const void* W2      = d_in[8];
    const void* b2      = d_in[9];
    const void* g2      = d_in[10];
    const void* be2     = d_in[11];
    char* ws = (char*)d_ws;

    int*   flag  = (int*)(ws + 0);
    float* sum1  = (float*)(ws + 4096);
    float* sq1   = (float*)(ws + 5120);
    float* sum2  = (float*)(ws + 6144);
    float* sq2   = (float*)(ws + 7168);
    int*   nidx  = (int*)(ws + 20480);             // 786432 B
    float* nw    = (float*)(ws + 806912);          // 786432 B, ends 1593344
    u16* Wa   = (u16*)(ws + 2097152);              // 256 KB  (W1[:, :512])
    u16* Wbp  = (u16*)(ws + 2359296);              // 128 KB  (W1[:, 512:])
    u16* W2b  = (u16*)(ws + 2490368);              // 128 KB
    u16* Z    = (u16*)(ws + 2621440);              // 8.4 MB  (16384 x 256)
    u16* y1   = (u16*)(ws + 11010048ULL);          // 33.6 MB (raw, pre-BN)
    u16* y2   = (u16*)(ws + 44564480ULL);          // 33.6 MB, ends 78118912

    Pointnet_fp_module_33071248179394_kernel<<<dim3(1024), dim3(256), 0, stream>>>(
        (const unsigned*)g1, flag, (float*)(ws + 4096), W1, W2, Wa, Wbp, W2b);
    three_nn_k<<<dim3(1024), dim3(512), 0, stream>>>(flag, xyz1, xyz2, nidx, nw);
    gemm_z_k<CC2, 2><<<dim3(MZ / 128, 2), dim3(256), 0, stream>>>(
        flag, points2, Wa, Z);
    gemm_mt_k<true, false><<<dim3(1024), dim3(256), 0, stream>>>(
        flag, points1, Wbp, b1, nidx, nw, Z, y1, sum1, sq1,
        nullptr, nullptr, nullptr, nullptr);
    gemm_mt_k<false, true><<<dim3(1024), dim3(256), 0, stream>>>(
        flag, y1, W2b, b2, nullptr, nullptr, nullptr, y2, sum2, sq2,
        sum1, sq1, g1, be1);
    bn_out_k<<<dim3(64, 4, NB), dim3(256), 0, stream>>>(
        flag, y2, d_out, sum2, sq2, g2, be2);
}